// Round 1
// baseline (421.597 us; speedup 1.0000x reference)
//
#include <hip/hip_runtime.h>
#include <hip/hip_bf16.h>

#define M_TOTAL (32 * 64 * 64)   // B*H*W = 131072 rows
#define CDIM 256
#define HDIM 1024

typedef float  floatx4 __attribute__((ext_vector_type(4)));
typedef short  short8  __attribute__((ext_vector_type(8)));

// ---------------------------------------------------------------------------
// Kernel 1: fused  x_new = x + LN1(x)  (fp32)   and   ln2 = LN2(x_new) (bf16)
// One wave (64 lanes) per row of 256 floats; 4 rows per 256-thread block.
// ---------------------------------------------------------------------------
__global__ __launch_bounds__(256) void ln_fused(
    const float* __restrict__ x,
    const float* __restrict__ g1, const float* __restrict__ b1,
    const float* __restrict__ g2, const float* __restrict__ b2,
    float* __restrict__ xnew, __hip_bfloat16* __restrict__ ln2o)
{
    const int  wave = threadIdx.x >> 6;
    const int  lane = threadIdx.x & 63;
    const long row  = (long)blockIdx.x * 4 + wave;

    const float4 v = ((const float4*)(x + row * CDIM))[lane];
    float s  = v.x + v.y + v.z + v.w;
    float sq = v.x * v.x + v.y * v.y + v.z * v.z + v.w * v.w;
#pragma unroll
    for (int o = 1; o < 64; o <<= 1) { s += __shfl_xor(s, o); sq += __shfl_xor(sq, o); }
    const float mu = s * (1.f / CDIM);
    const float rs = rsqrtf(sq * (1.f / CDIM) - mu * mu + 1e-5f);

    const float4 G1 = ((const float4*)g1)[lane];
    const float4 B1 = ((const float4*)b1)[lane];
    float4 xn;
    xn.x = v.x + (v.x - mu) * rs * G1.x + B1.x;
    xn.y = v.y + (v.y - mu) * rs * G1.y + B1.y;
    xn.z = v.z + (v.z - mu) * rs * G1.z + B1.z;
    xn.w = v.w + (v.w - mu) * rs * G1.w + B1.w;
    ((float4*)(xnew + row * CDIM))[lane] = xn;

    float s2 = xn.x + xn.y + xn.z + xn.w;
    float q2 = xn.x * xn.x + xn.y * xn.y + xn.z * xn.z + xn.w * xn.w;
#pragma unroll
    for (int o = 1; o < 64; o <<= 1) { s2 += __shfl_xor(s2, o); q2 += __shfl_xor(q2, o); }
    const float mu2 = s2 * (1.f / CDIM);
    const float rs2 = rsqrtf(q2 * (1.f / CDIM) - mu2 * mu2 + 1e-5f);

    const float4 G2 = ((const float4*)g2)[lane];
    const float4 B2 = ((const float4*)b2)[lane];
    union { ushort4 u; __hip_bfloat16 h[4]; } o4;
    o4.h[0] = __float2bfloat16((xn.x - mu2) * rs2 * G2.x + B2.x);
    o4.h[1] = __float2bfloat16((xn.y - mu2) * rs2 * G2.y + B2.y);
    o4.h[2] = __float2bfloat16((xn.z - mu2) * rs2 * G2.z + B2.z);
    o4.h[3] = __float2bfloat16((xn.w - mu2) * rs2 * G2.w + B2.w);
    ((ushort4*)(ln2o + row * CDIM))[lane] = o4.u;
}

// ---------------------------------------------------------------------------
// Kernel 2: transpose + fp32->bf16 convert.  src[R][Cc] f32 -> dst[Cc][R] bf16
// Writes coalesced (idx = c*R + r, r fastest).
// ---------------------------------------------------------------------------
__global__ __launch_bounds__(256) void transpose_cvt(
    const float* __restrict__ src, __hip_bfloat16* __restrict__ dst,
    int R, int Cc)
{
    const int idx = blockIdx.x * 256 + threadIdx.x;   // idx = c*R + r
    const int r = idx % R;
    const int c = idx / R;
    dst[idx] = __float2bfloat16(src[(long)r * Cc + c]);
}

// ---------------------------------------------------------------------------
// Kernel 3: bf16 MFMA GEMM, C = A[M][K] * Bt[N][K]^T, 128x128 tile, BK=32,
// 4 waves (2x2, 64x64 each), global_load_lds width-16 staging (m97 recipe).
// EPI==0: Cout = bf16 GELU(acc + bias)        (fc1 + exact GELU)
// EPI==1: Cout = f32  acc + bias + resid      (fc2 + residual)
// ---------------------------------------------------------------------------
template<int KTOT, int EPI>
__global__ __launch_bounds__(256) void gemm_bt(
    const __hip_bfloat16* __restrict__ A,
    const __hip_bfloat16* __restrict__ Bt,
    const float* __restrict__ bias,
    const float* __restrict__ resid,
    void* __restrict__ Cout, int Ncols)
{
    __shared__ __align__(16) __hip_bfloat16 As[128 * 32];
    __shared__ __align__(16) __hip_bfloat16 Bs[128 * 32];

    const int  tid  = threadIdx.x;
    const int  wave = tid >> 6;
    const int  lane = tid & 63;
    const long m0   = (long)blockIdx.y * 128;
    const int  n0   = blockIdx.x * 128;
    const int  wr   = (wave >> 1) * 64;    // wave row offset in tile
    const int  wc   = (wave & 1) * 64;     // wave col offset in tile
    const int  l4   = lane >> 2;           // 0..15 : row within 16-row chunk
    const int  ks   = lane & 3;            // 0..3  : 16B k-slot
    const int  fr   = lane & 15;
    const int  fq   = lane >> 4;

    floatx4 acc[4][4] = {};

    for (int k0 = 0; k0 < KTOT; k0 += 32) {
        __syncthreads();   // previous iteration's LDS reads complete
#pragma unroll
        for (int p = 0; p < 2; ++p) {
            const int chunk = p * 64 + wave * 16;   // 16 rows staged per wave-op
            const __hip_bfloat16* ga = A  + (m0 + chunk + l4) * (long)KTOT + k0 + ks * 8;
            __builtin_amdgcn_global_load_lds(
                (const __attribute__((address_space(1))) void*)(uintptr_t)ga,
                (__attribute__((address_space(3))) void*)(unsigned)(uintptr_t)(As + chunk * 32),
                16, 0, 0);
            const __hip_bfloat16* gb = Bt + ((long)(n0 + chunk + l4)) * KTOT + k0 + ks * 8;
            __builtin_amdgcn_global_load_lds(
                (const __attribute__((address_space(1))) void*)(uintptr_t)gb,
                (__attribute__((address_space(3))) void*)(unsigned)(uintptr_t)(Bs + chunk * 32),
                16, 0, 0);
        }
        __syncthreads();   // staged data visible (compiler drains vmcnt before barrier)

        short8 af[4], bf[4];
#pragma unroll
        for (int m = 0; m < 4; ++m)
            af[m] = *(const short8*)(As + (wr + m * 16 + fr) * 32 + fq * 8);
#pragma unroll
        for (int n = 0; n < 4; ++n)
            bf[n] = *(const short8*)(Bs + (wc + n * 16 + fr) * 32 + fq * 8);
#pragma unroll
        for (int m = 0; m < 4; ++m)
#pragma unroll
            for (int n = 0; n < 4; ++n)
                acc[m][n] = __builtin_amdgcn_mfma_f32_16x16x32_bf16(
                    af[m], bf[n], acc[m][n], 0, 0, 0);
    }

    // Epilogue.  C/D layout (m89-verified): col = lane&15, row = (lane>>4)*4 + reg
    if (EPI == 0) {
        __hip_bfloat16* Cb = (__hip_bfloat16*)Cout;
#pragma unroll
        for (int m = 0; m < 4; ++m) {
#pragma unroll
            for (int n = 0; n < 4; ++n) {
                const int   col = n0 + wc + n * 16 + fr;
                const float bb  = bias[col];
#pragma unroll
                for (int j = 0; j < 4; ++j) {
                    const long row = m0 + wr + m * 16 + fq * 4 + j;
                    const float v = acc[m][n][j] + bb;
                    const float g = 0.5f * v * (1.0f + erff(v * 0.70710678f));
                    Cb[row * Ncols + col] = __float2bfloat16(g);
                }
            }
        }
    } else {
        float* Cf = (float*)Cout;
#pragma unroll
        for (int m = 0; m < 4; ++m) {
#pragma unroll
            for (int n = 0; n < 4; ++n) {
                const int   col = n0 + wc + n * 16 + fr;
                const float bb  = bias[col];
#pragma unroll
                for (int j = 0; j < 4; ++j) {
                    const long row = m0 + wr + m * 16 + fq * 4 + j;
                    Cf[row * Ncols + col] = acc[m][n][j] + bb + resid[row * Ncols + col];
                }
            }
        }
    }
}

// ---------------------------------------------------------------------------
extern "C" void kernel_launch(void* const* d_in, const int* in_sizes, int n_in,
                              void* d_out, int out_size, void* d_ws, size_t ws_size,
                              hipStream_t stream)
{
    const float* x    = (const float*)d_in[0];
    const float* ln1g = (const float*)d_in[1];
    const float* ln1b = (const float*)d_in[2];
    const float* ln2g = (const float*)d_in[3];
    const float* ln2b = (const float*)d_in[4];
    const float* w1   = (const float*)d_in[5];
    const float* b1   = (const float*)d_in[6];
    const float* w2   = (const float*)d_in[7];
    const float* b2   = (const float*)d_in[8];
    float* out = (float*)d_out;

    // workspace layout (bytes)
    char* ws = (char*)d_ws;
    float*          xnew = (float*)ws;                                // 134,217,728
    __hip_bfloat16* ln2o = (__hip_bfloat16*)(ws + 134217728);         //  67,108,864
    __hip_bfloat16* act  = (__hip_bfloat16*)(ws + 201326592);         // 268,435,456
    __hip_bfloat16* w1t  = (__hip_bfloat16*)(ws + 469762048);         //     524,288
    __hip_bfloat16* w2t  = (__hip_bfloat16*)(ws + 470286336);         //     524,288

    // 1) fused LN1-residual + LN2
    ln_fused<<<M_TOTAL / 4, 256, 0, stream>>>(x, ln1g, ln1b, ln2g, ln2b, xnew, ln2o);

    // 2) weight transpose + bf16 convert
    transpose_cvt<<<(CDIM * HDIM) / 256, 256, 0, stream>>>(w1, w1t, CDIM, HDIM); // w1t[1024][256]
    transpose_cvt<<<(CDIM * HDIM) / 256, 256, 0, stream>>>(w2, w2t, HDIM, CDIM); // w2t[256][1024]

    // 3) fc1 + GELU :  act[M][1024] = GELU(ln2o[M][256] @ w1 + b1)
    gemm_bt<CDIM, 0><<<dim3(HDIM / 128, M_TOTAL / 128), 256, 0, stream>>>(
        ln2o, w1t, b1, nullptr, (void*)act, HDIM);

    // 4) fc2 + residual :  out[M][256] = act @ w2 + b2 + xnew
    gemm_bt<HDIM, 1><<<dim3(CDIM / 128, M_TOTAL / 128), 256, 0, stream>>>(
        act, w2t, b2, xnew, (void*)out, CDIM);
}